// Round 19
// baseline (431.321 us; speedup 1.0000x reference)
//
#include <hip/hip_runtime.h>
#include <math.h>

#define C_    768
#define H_    12
#define D_    64
#define B_    8
#define T_    512
#define TM1   511
#define R_    8
#define KN_   4
#define KC5   5
#define SCALE_ 0.5f
#define EPS_  1e-12f
#define NEG_  -1000000000.0f
#define INV_  0.125f
#define LDQ   2432     /* Q|K|Vp|qp(128) */
#define QPOFF 2304
#define LDVQ  896      /* vqn row: Vp(768)|qp(128) */
#define NT_   4096
#define NRR_  16352

typedef __bf16 bf16_t;
typedef __bf16 bf16x4_t __attribute__((ext_vector_type(4)));
typedef __bf16 bf16x8_t __attribute__((ext_vector_type(8)));
typedef float  f32x4_t  __attribute__((ext_vector_type(4)));
typedef const void __attribute__((address_space(1)))* gas_t;
typedef void       __attribute__((address_space(3)))* las_t;

__device__ __forceinline__ void gl_lds16(const bf16_t* g, bf16_t* l) {
  __builtin_amdgcn_global_load_lds((gas_t)g, (las_t)l, 16, 0, 0);
}

__device__ __forceinline__ int swz(int row, int g) {
  return row * 32 + (((g ^ (row >> 1)) & 3) << 3);
}

struct GemmDesc {
  const bf16_t* A; int lda;
  const bf16_t* Bt;
  const float* bias;
  bf16_t* Cbf; int ldc;
  bf16_t* Ctr; int trcol0; int mode;
  int M, K, N, gx, nwg;
};

// ---------------------------------------------------------------------------
// PREP: conversions + weight prep (round-15/16 verified).
// ---------------------------------------------------------------------------
__global__ __launch_bounds__(256) void prep(
    const float* __restrict__ x, const float* __restrict__ nrep,
    const float* __restrict__ Wq, const float* __restrict__ Wk,
    const float* __restrict__ Wv, const float* __restrict__ Wp,
    const float* __restrict__ Wd, const float* __restrict__ Wu,
    const float* __restrict__ bq, const float* __restrict__ bk,
    const float* __restrict__ bv, const float* __restrict__ bu,
    const float* __restrict__ bp,
    bf16_t* __restrict__ xbf, bf16_t* __restrict__ nrbf,
    bf16_t* __restrict__ Wbig, bf16_t* __restrict__ Wtp,
    bf16_t* __restrict__ Wvbf,
    float* __restrict__ WdT, float* __restrict__ bbig,
    float* __restrict__ zb768)
{
  __shared__ float tile[32][33];
  const int bid = blockIdx.x, tid = threadIdx.x;
  if (bid < 1024) {
    const long n = (long)NT_ * C_;
    for (long i = ((long)bid * 256 + tid) * 4; i < n; i += (long)1024 * 256 * 4) {
      float4 v = *(const float4*)(x + i);
      bf16x4_t o = {(bf16_t)v.x, (bf16_t)v.y, (bf16_t)v.z, (bf16_t)v.w};
      *(bf16x4_t*)(xbf + i) = o;
    }
  } else if (bid < 3072) {
    const long n = (long)NRR_ * C_;
    for (long i = ((long)(bid - 1024) * 256 + tid) * 4; i < n;
         i += (long)2048 * 256 * 4) {
      float4 v = *(const float4*)(nrep + i);
      bf16x4_t o = {(bf16_t)v.x, (bf16_t)v.y, (bf16_t)v.z, (bf16_t)v.w};
      *(bf16x4_t*)(nrbf + i) = o;
    }
  } else if (bid < 5376) {
    int sub = bid - 3072;
    const int which = sub / 576; sub %= 576;
    if (which == 2) {
      const long i = ((long)sub * 256 + tid) * 4;
      float4 v = *(const float4*)(Wv + i);
      bf16x4_t o = {(bf16_t)v.x, (bf16_t)v.y, (bf16_t)v.z, (bf16_t)v.w};
      *(bf16x4_t*)(Wvbf + i) = o;
    } else {
      const float* W = which == 0 ? Wq : which == 1 ? Wk : Wp;
      bf16_t* Wt = (which == 3) ? Wtp : Wbig + (size_t)which * C_ * C_;
      const int n0 = (sub % 24) * 32, k0 = (sub / 24) * 32;
      const int tx = tid & 31, ty = tid >> 5;
      #pragma unroll
      for (int r = ty; r < 32; r += 8)
        tile[r][tx] = W[(size_t)(k0 + r) * C_ + n0 + tx];
      __syncthreads();
      #pragma unroll
      for (int r = ty; r < 32; r += 8)
        Wt[(size_t)(n0 + r) * C_ + k0 + tx] = (bf16_t)tile[tx][r];
    }
  } else if (bid < 5760) {
    const int idx = (bid - 5376) * 256 + tid;
    const int n = idx / C_, k = idx % C_;
    const int h = n / 10, r = n % 10;
    float s = 0.f;
    if (h < H_ && r < 9) {
      if (r < 8) {
        #pragma unroll 8
        for (int j = 0; j < 64; ++j)
          s += Wu[r * C_ + h * 64 + j] * Wq[(size_t)k * C_ + h * 64 + j];
      } else {
        #pragma unroll 8
        for (int j = 0; j < 64; ++j)
          s += bu[h * 64 + j] * Wq[(size_t)k * C_ + h * 64 + j];
      }
    }
    Wbig[(size_t)(QPOFF + n) * C_ + k] = (bf16_t)s;
  } else if (bid < 5784) {
    const int idx = (bid - 5760) * 256 + tid;
    if (idx < R_ * C_) {
      const int r = idx / C_, k = idx % C_;
      WdT[idx] = Wd[(size_t)k * R_ + r];
    }
  } else {
    const int i = (bid - 5784) * 256 + tid;
    if (i < LDQ) {
      float v;
      if (i < 768) v = bq[i];
      else if (i < 1536) v = bk[i - 768];
      else if (i < 2304) {
        const int n = i - 1536;
        float s = bp[n];
        for (int m = 0; m < C_; ++m) s += bv[m] * Wp[(size_t)m * C_ + n];
        v = s;
      } else {
        const int n = i - QPOFF, h = n / 10, r = n % 10;
        v = 0.f;
        if (h < H_ && r < 9) {
          if (r < 8) {
            float s = 0.f;
            for (int j = 0; j < 64; ++j) s += bq[h * 64 + j] * Wu[r * C_ + h * 64 + j];
            v = s;
          } else {
            float s = 0.f;
            for (int j = 0; j < 64; ++j) s += bq[h * 64 + j] * bu[h * 64 + j];
            v = s;
          }
        }
      }
      bbig[i] = v;
    } else if (i < LDQ + 768) {
      zb768[i - LDQ] = 0.f;
    }
  }
}

// ---------------------------------------------------------------------------
// GEMM body: 128x128 tile, BK=32 double-buffered, counted vmcnt(4) pipeline
// (round-18 measured structure).
// ---------------------------------------------------------------------------
__device__ __forceinline__ void gemm_body(const GemmDesc& d, int bid0, char* pool)
{
  bf16_t* Cs = (bf16_t*)pool;

  int lid = bid0;
  {
    const int nwg = d.nwg;
    const int q0 = nwg >> 3, r0 = nwg & 7;
    const int xcd = lid & 7, idx = lid >> 3;
    lid = (xcd < r0 ? xcd * (q0 + 1) : r0 * (q0 + 1) + (xcd - r0) * q0) + idx;
  }
  const int row0 = (lid / d.gx) * 128;
  const int col0 = (lid % d.gx) * 128;

  const int tid = threadIdx.x;
  const int lane = tid & 63;
  const int wv = tid >> 6;
  const int wr = (wv >> 1) * 64;
  const int wc = (wv & 1) * 64;
  const int wvo = wv * 512;

  const int sr = tid >> 2;
  const int ssl = (tid & 3) ^ ((sr >> 1) & 3);
  const int sk = ssl * 8;

  int ra0 = row0 + sr;       if (ra0 > d.M - 1) ra0 = d.M - 1;
  int ra1 = row0 + 64 + sr;  if (ra1 > d.M - 1) ra1 = d.M - 1;
  const bf16_t* ga0 = d.A + (size_t)ra0 * d.lda + sk;
  const bf16_t* ga1 = d.A + (size_t)ra1 * d.lda + sk;
  const bf16_t* gb0 = d.Bt + (size_t)(col0 + sr) * d.K + sk;
  const bf16_t* gb1 = d.Bt + (size_t)(col0 + 64 + sr) * d.K + sk;

  f32x4_t acc[4][4];
  #pragma unroll
  for (int i = 0; i < 4; ++i)
    #pragma unroll
    for (int j = 0; j < 4; ++j) acc[i][j] = (f32x4_t){0.f, 0.f, 0.f, 0.f};

  const int fm = lane & 15;
  const int g = lane >> 4;

  {
    bf16_t* a0 = (bf16_t*)pool;
    bf16_t* b0 = (bf16_t*)(pool + 8192);
    gl_lds16(ga0, a0 + wvo);
    gl_lds16(ga1, a0 + 2048 + wvo);
    gl_lds16(gb0, b0 + wvo);
    gl_lds16(gb1, b0 + 2048 + wvo);
  }

  unsigned cur = 0;
  for (int k0 = 0; k0 < d.K; k0 += 32) {
    if (k0 + 32 < d.K) {
      char* nb = pool + ((cur ^ 1u) << 14);
      bf16_t* na = (bf16_t*)nb;
      bf16_t* nbb = (bf16_t*)(nb + 8192);
      gl_lds16(ga0 + k0 + 32, na + wvo);
      gl_lds16(ga1 + k0 + 32, na + 2048 + wvo);
      gl_lds16(gb0 + k0 + 32, nbb + wvo);
      gl_lds16(gb1 + k0 + 32, nbb + 2048 + wvo);
      asm volatile("s_waitcnt vmcnt(4)" ::: "memory");
    } else {
      asm volatile("s_waitcnt vmcnt(0)" ::: "memory");
    }
    __builtin_amdgcn_s_barrier();
    {
      const bf16_t* cA = (const bf16_t*)(pool + (cur << 14));
      const bf16_t* cB = (const bf16_t*)(pool + (cur << 14) + 8192);
      bf16x8_t af[4], bfr[4];
      #pragma unroll
      for (int mi = 0; mi < 4; ++mi)
        af[mi] = *(const bf16x8_t*)(cA + swz(wr + mi * 16 + fm, g));
      #pragma unroll
      for (int ni = 0; ni < 4; ++ni)
        bfr[ni] = *(const bf16x8_t*)(cB + swz(wc + ni * 16 + fm, g));
      __builtin_amdgcn_s_setprio(1);
      #pragma unroll
      for (int mi = 0; mi < 4; ++mi)
        #pragma unroll
        for (int ni = 0; ni < 4; ++ni)
          acc[mi][ni] = __builtin_amdgcn_mfma_f32_16x16x32_bf16(af[mi], bfr[ni],
                                                                acc[mi][ni], 0, 0, 0);
      __builtin_amdgcn_s_setprio(0);
    }
    __builtin_amdgcn_s_barrier();
    cur ^= 1u;
  }

  const int r4 = (lane >> 4) * 4;

  if (d.mode & 2) {
    #pragma unroll
    for (int ni = 0; ni < 4; ++ni) {
      const int col = col0 + wc + ni * 16 + fm;
      if ((unsigned)(col - d.trcol0) < 768u) {
        const int vcol = col - d.trcol0;
        const float bv = d.bias[col];
        #pragma unroll
        for (int mi = 0; mi < 4; ++mi) {
          const int rb = row0 + wr + mi * 16 + r4;
          bf16x4_t o4 = {(bf16_t)(acc[mi][ni][0] + bv), (bf16_t)(acc[mi][ni][1] + bv),
                         (bf16_t)(acc[mi][ni][2] + bv), (bf16_t)(acc[mi][ni][3] + bv)};
          size_t idx = ((size_t)(rb >> 9) * H_ + (size_t)(vcol >> 6)) * ((size_t)D_ * T_)
                     + (size_t)(vcol & 63) * T_ + (size_t)(rb & 511);
          *(bf16x4_t*)(d.Ctr + idx) = o4;
        }
      }
    }
  }

  #pragma unroll
  for (int p = 0; p < 2; ++p) {
    if (wr == p * 64) {
      #pragma unroll
      for (int ni = 0; ni < 4; ++ni) {
        const int col = wc + ni * 16 + fm;
        const float bv = d.bias[col0 + col];
        #pragma unroll
        for (int mi = 0; mi < 4; ++mi) {
          const int lrow = mi * 16 + r4;
          #pragma unroll
          for (int r = 0; r < 4; ++r)
            Cs[(lrow + r) * 136 + col] = (bf16_t)(acc[mi][ni][r] + bv);
        }
      }
    }
    __syncthreads();
    const int rrow = tid >> 2;
    const int cc = (tid & 3) * 32;
    const int grow = row0 + p * 64 + rrow;
    if ((d.mode & 1) && grow < d.M) {
      bf16_t* gp = d.Cbf + (size_t)grow * d.ldc + col0 + cc;
      const bf16_t* lp = Cs + rrow * 136 + cc;
      #pragma unroll
      for (int j = 0; j < 4; ++j)
        *(bf16x8_t*)(gp + j * 8) = *(const bf16x8_t*)(lp + j * 8);
    }
    __syncthreads();
  }
}

// ---------------------------------------------------------------------------
// Coalesced low-rank GEMV (round-11 verified).
// ---------------------------------------------------------------------------
__device__ __forceinline__ void gemv8w_body(
    const bf16_t* __restrict__ A, const float* __restrict__ WdT,
    const float* __restrict__ bd, float* __restrict__ out, int M, int bid)
{
  const int w = (int)threadIdx.x >> 6, lane = (int)threadIdx.x & 63;
  const int row0 = bid * 16 + w * 4;
  #pragma unroll
  for (int rr = 0; rr < 4; ++rr) {
    const int row = row0 + rr;
    if (row >= M) return;
    const bf16_t* ar = A + (size_t)row * C_ + lane * 12;
    float xv[12];
    #pragma unroll
    for (int c = 0; c < 3; ++c) {
      bf16x4_t v = *(const bf16x4_t*)(ar + c * 4);
      #pragma unroll
      for (int j = 0; j < 4; ++j) xv[c * 4 + j] = (float)v[j];
    }
    float acc[8];
    #pragma unroll
    for (int r = 0; r < 8; ++r) {
      const float* wr = WdT + r * C_ + lane * 12;
      float4 w0 = *(const float4*)(wr);
      float4 w1 = *(const float4*)(wr + 4);
      float4 w2 = *(const float4*)(wr + 8);
      acc[r] = xv[0]*w0.x + xv[1]*w0.y + xv[2]*w0.z + xv[3]*w0.w
             + xv[4]*w1.x + xv[5]*w1.y + xv[6]*w1.z + xv[7]*w1.w
             + xv[8]*w2.x + xv[9]*w2.y + xv[10]*w2.z + xv[11]*w2.w;
    }
    #pragma unroll
    for (int off = 32; off > 0; off >>= 1) {
      #pragma unroll
      for (int r = 0; r < 8; ++r) acc[r] += __shfl_xor(acc[r], off);
    }
    if (lane == 0) {
      #pragma unroll
      for (int r = 0; r < 8; ++r)
        out[(size_t)row * R_ + r] = acc[r] + bd[r];
    }
  }
}

// MEGA1: QKV-GEMM | vqn-GEMM | gemv(t1) | gemv(t2) in one dispatch.
// __launch_bounds__(256,5): cap VGPR at 102 -> 5 blocks/CU (LDS allows 5).
__global__ __launch_bounds__(256, 5) void mega1(
    GemmDesc d0, int n0, GemmDesc d1, int n1,
    const bf16_t* Ag1, const bf16_t* Ag2,
    const float* WdT, const float* bd,
    float* o1, int M1, int ng1, float* o2, int M2)
{
  __shared__ __align__(16) char pool[32768];
  int bid = blockIdx.x;
  if (bid < n0) { gemm_body(d0, bid, pool); return; }
  bid -= n0;
  if (bid < n1) { gemm_body(d1, bid, pool); return; }
  bid -= n1;
  if (bid < ng1) { gemv8w_body(Ag1, WdT, bd, o1, M1, bid); return; }
  bid -= ng1;
  gemv8w_body(Ag2, WdT, bd, o2, M2, bid);
}

// standalone GEMM (wvp weight fusion)
__global__ __launch_bounds__(256, 5) void gemm_mfma_k(GemmDesc d) {
  __shared__ __align__(16) char pool[32768];
  gemm_body(d, blockIdx.x, pool);
}

// ---------------------------------------------------------------------------
// attn / cls / neigh bodies (round-17/18 verified).
// ---------------------------------------------------------------------------
__device__ void attn_body(
    const bf16_t* __restrict__ QKVc, const bf16_t* __restrict__ Vtg,
    const int* __restrict__ mask, bf16_t* __restrict__ yout,
    char* pool, int bid)
{
  bf16_t* Ks   = (bf16_t*)pool;
  bf16_t* Vs   = (bf16_t*)(pool + 8192);
  bf16_t* Pl   = (bf16_t*)(pool + 16384);
  float* fac_s = (float*)(pool + 24576);
  float* l_s   = (float*)(pool + 24832);
  int*   msk_s = (int*)(pool + 25088);

  const int qt0 = (bid & 7) * 64;
  const int h = (bid >> 3) % H_;
  const int b = bid / 96;
  const int tid = threadIdx.x;
  const int lane = tid & 63;
  const int w = tid >> 6;
  const int lq = lane & 15;
  const int g = lane >> 4;

  const int qi_frag = qt0 + w * 16 + lq;
  const int qtok = (qi_frag < TM1 ? qi_frag : TM1 - 1) + 1;
  bf16x8_t qf[2];
  {
    const bf16_t* qp = QKVc + ((size_t)(b * T_) + qtok) * LDQ + h * D_ + 8 * g;
    qf[0] = *(const bf16x8_t*)qp;
    qf[1] = *(const bf16x8_t*)(qp + 32);
  }

  const bf16_t* kbase = QKVc + (size_t)(b * T_) * LDQ + 768 + h * D_;
  const bf16_t* vbase = Vtg + ((size_t)(b * H_) + h) * ((size_t)D_ * T_);

  f32x4_t o[4];
  #pragma unroll
  for (int i = 0; i < 4; ++i) o[i] = (f32x4_t){0.f, 0.f, 0.f, 0.f};
  float m = -INFINITY, l = 0.f;

  for (int kt = 0; kt < T_; kt += 64) {
    #pragma unroll
    for (int i = 0; i < 2; ++i) {
      const int tp = tid + i * 256;
      const int kr = tp >> 3;
      const int sl = tp & 7;
      const int ss = sl ^ (kr & 7);
      gl_lds16(kbase + (size_t)(kt + kr) * LDQ + 8 * ss,
               Ks + (size_t)(i * 4 + w) * 512);
      gl_lds16(vbase + (size_t)kr * T_ + kt + 8 * ss,
               Vs + (size_t)(i * 4 + w) * 512);
    }
    if (tid < 64) msk_s[tid] = mask[b * T_ + kt + tid];
    __syncthreads();

    f32x4_t st[4];
    __builtin_amdgcn_s_setprio(1);
    #pragma unroll
    for (int t = 0; t < 4; ++t) {
      st[t] = (f32x4_t){0.f, 0.f, 0.f, 0.f};
      const int kk = t * 16 + lq;
      const bf16_t* krow = Ks + kk * 64;
      bf16x8_t kf0 = *(const bf16x8_t*)(krow + 8 * ((g)     ^ (kk & 7)));
      bf16x8_t kf1 = *(const bf16x8_t*)(krow + 8 * ((4 + g) ^ (kk & 7)));
      st[t] = __builtin_amdgcn_mfma_f32_16x16x32_bf16(kf0, qf[0], st[t], 0, 0, 0);
      st[t] = __builtin_amdgcn_mfma_f32_16x16x32_bf16(kf1, qf[1], st[t], 0, 0, 0);
    }
    __builtin_amdgcn_s_setprio(0);

    float p[16];
    float mt = -INFINITY;
    #pragma unroll
    for (int t = 0; t < 4; ++t) {
      const int4 mk = *(const int4*)&msk_s[t * 16 + 4 * g];
      p[4*t+0] = mk.x ? st[t][0] * INV_ : NEG_;
      p[4*t+1] = mk.y ? st[t][1] * INV_ : NEG_;
      p[4*t+2] = mk.z ? st[t][2] * INV_ : NEG_;
      p[4*t+3] = mk.w ? st[t][3] * INV_ : NEG_;
      mt = fmaxf(mt, fmaxf(fmaxf(p[4*t], p[4*t+1]), fmaxf(p[4*t+2], p[4*t+3])));
    }
    mt = fmaxf(mt, __shfl_xor(mt, 16));
    mt = fmaxf(mt, __shfl_xor(mt, 32));
    const float mnew = fmaxf(m, mt);
    const float fac = __expf(m - mnew);
    float ps = 0.f;
    #pragma unroll
    for (int i = 0; i < 16; ++i) { p[i] = __expf(p[i] - mnew); ps += p[i]; }
    ps += __shfl_xor(ps, 16);
    ps += __shfl_xor(ps, 32);
    l = l * fac + ps;
    m = mnew;
    if (lane < 16) fac_s[w * 16 + lane] = fac;

    bf16_t* prow = Pl + w * 1024 + lq * 64;
    #pragma unroll
    for (int t = 0; t < 4; ++t) {
      bf16x4_t pb = {(bf16_t)p[4*t], (bf16_t)p[4*t+1],
                     (bf16_t)p[4*t+2], (bf16_t)p[4*t+3]};
      *(bf16x4_t*)(prow + 8 * ((2*t + (g >> 1)) ^ (lq & 7)) + 4 * (g & 1)) = pb;
    }
    bf16x8_t pa0 = *(const bf16x8_t*)(prow + 8 * ((g)     ^ (lq & 7)));
    bf16x8_t pa1 = *(const bf16x8_t*)(prow + 8 * ((4 + g) ^ (lq & 7)));

    const float4 fc = *(const float4*)&fac_s[w * 16 + 4 * g];
    __builtin_amdgcn_s_setprio(1);
    #pragma unroll
    for (int db = 0; db < 4; ++db) {
      const int dr = db * 16 + lq;
      const bf16_t* vrow = Vs + dr * 64;
      bf16x8_t vf0 = *(const bf16x8_t*)(vrow + 8 * ((g)     ^ (dr & 7)));
      bf16x8_t vf1 = *(const bf16x8_t*)(vrow + 8 * ((4 + g) ^ (dr & 7)));
      o[db][0] *= fc.x; o[db][1] *= fc.y; o[db][2] *= fc.z; o[db][3] *= fc.w;
      o[db] = __builtin_amdgcn_mfma_f32_16x16x32_bf16(pa0, vf0, o[db], 0, 0, 0);
      o[db] = __builtin_amdgcn_mfma_f32_16x16x32_bf16(pa1, vf1, o[db], 0, 0, 0);
    }
    __builtin_amdgcn_s_setprio(0);
    __syncthreads();
  }

  if (lane < 16) l_s[w * 16 + lane] = l;
  const float4 lv = *(const float4*)&l_s[w * 16 + 4 * g];
  const float rl0 = 1.f / lv.x, rl1 = 1.f / lv.y;
  const float rl2 = 1.f / lv.z, rl3 = 1.f / lv.w;
  const int qr0 = qt0 + w * 16 + 4 * g;
  #pragma unroll
  for (int db = 0; db < 4; ++db) {
    const int col = h * D_ + db * 16 + lq;
    bf16_t* yp = yout + ((size_t)(b * TM1) + qr0) * C_ + col;
    if (qr0 + 0 < TM1) yp[0 * (size_t)C_] = (bf16_t)(o[db][0] * rl0);
    if (qr0 + 1 < TM1) yp[1 * (size_t)C_] = (bf16_t)(o[db][1] * rl1);
    if (qr0 + 2 < TM1) yp[2 * (size_t)C_] = (bf16_t)(o[db][2] * rl2);
    if (qr0 + 3 < TM1) yp[3 * (size_t)C_] = (bf16_t)(o[db][3] * rl3);
  }
}

__device__ void cls_body(
    const bf16_t* __restrict__ QKVc, const float* __restrict__ t1,
    const int* __restrict__ mask, float* __restrict__ ycp,
    char* pool, int cbid)
{
  float* Vs   = (float*)pool;
  float* Ps   = (float*)(pool + 16640);
  float* qp_s = (float*)(pool + 16960);

  const int b = cbid / H_, h = cbid % H_;
  const int tid = threadIdx.x;
  const int lane = tid & 63;

  if (tid < 9)
    qp_s[tid] = (float)QKVc[(size_t)(b * T_) * LDQ + QPOFF + h * 10 + tid];
  __syncthreads();

  float m = -INFINITY, l = 0.f, acc = 0.f, mnew = 0.f;
  for (int kt = 0; kt < T_; kt += 64) {
    for (int rr = tid >> 6; rr < 64; rr += 4)
      Vs[rr * 65 + lane] =
          (float)QKVc[((size_t)(b * T_) + kt + rr) * LDQ + 1536 + h * D_ + lane];
    __syncthreads();
    if (tid < 64) {
      const float* t1r = t1 + ((size_t)(b * T_) + kt + tid) * R_;
      float sc = qp_s[8];
      #pragma unroll
      for (int r = 0; r < 8; ++r) sc += qp_s[r] * t1r[r];
      sc *= INV_;
      if (!mask[b * T_ + kt + tid]) sc = NEG_;
      float mt = sc;
      #pragma unroll
      for (int off = 32; off > 0; off >>= 1) mt = fmaxf(mt, __shfl_xor(mt, off));
      mnew = fmaxf(m, mt);
      float e = __expf(sc - mnew);
      float ssum = e;
      #pragma unroll
      for (int off = 32; off > 0; off >>= 1) ssum += __shfl_xor(ssum, off);
      float fac = __expf(m - mnew);
      acc *= fac;
      l = l * fac + ssum;
      Ps[tid] = e;
    }
    __syncthreads();
    if (tid < 64) {
      #pragma unroll
      for (int j = 0; j < 64; ++j) acc += Ps[j] * Vs[j * 65 + tid];
      m = mnew;
    }
    __syncthreads();
  }
  if (tid < 64) ycp[(size_t)b * C_ + h * D_ + tid] = acc / l;
}

__device__ void neigh_body(
    const bf16_t* __restrict__ QKVc, const float* __restrict__ t1,
    const bf16_t* __restrict__ vqn, const float* __restrict__ t2,
    int b0, bf16_t* __restrict__ poutn, char* pool, int bt)
{
  float* vs   = (float*)pool;
  float* qp_s = (float*)(pool + 15360);
  float* t2_s = (float*)(pool + 17920);
  float* Ps   = (float*)(pool + 18080);

  const int tid = threadIdx.x;
  const int bb = bt / TM1, t = bt % TM1;
  const int b = b0 + bb;
  const size_t tok = (size_t)(b * T_) + t + 1;
  const size_t nrow = ((size_t)(bb * TM1) + t) * KN_;

  for (int idx = tid; idx < KC5 * 96; idx += 256) {
    int i = idx / 96, d8 = (idx % 96) * 8;
    const bf16_t* vp = (i == 0) ? QKVc + tok * LDQ + 1536 + d8
                                : vqn + (nrow + i - 1) * LDVQ + d8;
    bf16x8_t vv = *(const bf16x8_t*)vp;
    #pragma unroll
    for (int j = 0; j < 8; ++j) vs[i * C_ + d8 + j] = (float)vv[j];
  }
  for (int idx = tid; idx < KC5 * 16; idx += 256) {
    int i = idx / 16, c8 = (idx % 16) * 8;
    const bf16_t* qpp = (i == 0) ? QKVc + tok * LDQ + QPOFF + c8
                                 : vqn + (nrow + i - 1) * LDVQ + 768 + c8;
    bf16x8_t qv = *(const bf16x8_t*)qpp;
    #pragma unroll
    for (int j = 0; j < 8; ++j) qp_s[i * 128 + c8 + j] = (float)qv[j];
  }
  if (tid < KC5 * 8) {
    int i = tid / 8, r = tid & 7;
    t2_s[i * 8 + r] = (i == 0) ? t1[tok * R_ + r] : t2[(nrow + i - 1) * R_ + r];
  }
  __syncthreads();

  if (tid < H_ * KC5) {
    int h = tid / KC5, i = tid % KC5;
    float sc[KC5];
    #pragma unroll
    for (int j = 0; j < KC5; ++j) {
      float s = qp_s[i * 128 + h * 10 + 8];
      #pragma unroll
      for (int r = 0; r < 8; ++r) s += qp_s[i * 128 + h * 10 + r] * t2_s[j * 8 + r];
      sc[j] = s * INV_;
    }
    float mt = sc[0];
    #pragma unroll
    for (int j = 1; j < KC5; ++j) mt = fmaxf(mt, sc[j]);
    float e[KC5], ssum = 0.f;
    #pragma unroll
    for (int j = 0; j < KC5; ++j) { e[j] = __expf(sc[j] - mt); ssum += e[j]; }
    float rs = 1.f / ssum;
    #pragma unroll
    for (int j = 0; j < KC5; ++j) Ps[h * 25 + i * KC5 + j] = e[j] * rs;
  }
  __syncthreads();

  for (int idx = tid; idx < KC5 * C_; idx += 256) {
    int i = idx / C_, c = idx % C_;
    int h = c / D_;
    float sum = 0.f;
    #pragma unroll
    for (int j = 0; j < KC5; ++j)
      sum += Ps[h * 25 + i * KC5 + j] * vs[j * C_ + c];
    poutn[(((size_t)(bb * TM1) + t) * KC5 + i) * C_ + c] = (bf16_t)sum;
  }
}

__global__ __launch_bounds__(256) void attn_neigh(
    int nAttn, int nCls,
    const bf16_t* __restrict__ QKVc, const bf16_t* __restrict__ Vtg,
    const int* __restrict__ mask, bf16_t* __restrict__ ysp,
    const float* __restrict__ t1, float* __restrict__ ycp,
    const bf16_t* __restrict__ vqn, const float* __restrict__ t2,
    int b0, bf16_t* __restrict__ poutn)
{
  __shared__ __align__(16) char pool[25344];
  int bid = blockIdx.x;
  if (bid < nAttn) { attn_body(QKVc, Vtg, mask, ysp, pool, bid); return; }
  bid -= nAttn;
  if (bid < nCls) { cls_body(QKVc, t1, mask, ycp, pool, bid); return; }
  bid -= nCls;
  neigh_body(QKVc, t1, vqn, t2, b0, poutn, pool, bid);
}

// ---------------------------------------------------------------------------
// COMBINE: main (with y_self blend) + neigh + cls residual-LN.
// ---------------------------------------------------------------------------
__device__ __forceinline__ void block_reduce2(float& s, float& ss, float* red) {
  #pragma unroll
  for (int off = 32; off > 0; off >>= 1) {
    s += __shfl_down(s, off);
    ss += __shfl_down(ss, off);
  }
  int wid = threadIdx.x >> 6;
  if ((threadIdx.x & 63) == 0) { red[wid * 2] = s; red[wid * 2 + 1] = ss; }
  __syncthreads();
  s  = red[0] + red[2] + red[4] + red[6];
  ss = red[1] + red[3] + red[5] + red[7];
}

__device__ __forceinline__ void ln_row(const float vals[3], float s, float ss,
                                       const float* __restrict__ g,
                                       const float* __restrict__ bb,
                                       float* __restrict__ orow, float* red) {
  block_reduce2(s, ss, red);
  float mean = s * (1.f / (float)C_);
  float var = ss * (1.f / (float)C_) - mean * mean;
  var = fmaxf(var, 0.f);
  float rs = rsqrtf(var + EPS_);
  #pragma unroll
  for (int ii = 0; ii < 3; ++ii) {
    int c = threadIdx.x + ii * 256;
    orow[c] = (vals[ii] - mean) * rs * g[c] + bb[c];
  }
}

__global__ __launch_bounds__(256) void combine_all(
    const bf16_t* __restrict__ poutnb, const bf16_t* __restrict__ ysp,
    const float* __restrict__ x,
    const float* __restrict__ g, const float* __restrict__ bln,
    int b0, float* __restrict__ dout, float* __restrict__ dout1,
    const bf16_t* __restrict__ nrcbf, int nMain,
    const float* __restrict__ ycp)
{
  __shared__ float red[8];
  int bid = blockIdx.x;
  float vals[3], s = 0.f, ss = 0.f;
  if (bid < nMain) {
    const int bbb = bid / TM1, t = bid % TM1;
    const int b = b0 + bbb;
    const bf16_t* pn = poutnb + (((size_t)(bbb * TM1) + t) * KC5 + 0) * C_;
    const bf16_t* ys = ysp + ((size_t)(b * TM1) + t) * C_;
    const float* xr = x + ((size_t)(b * T_) + t + 1) * C_;
    float* orow = dout + ((size_t)(b * T_) + t + 1) * C_;
    #pragma unroll
    for (int ii = 0; ii < 3; ++ii) {
      int c = threadIdx.x + ii * 256;
      float v = SCALE_ * (float)pn[c] + (1.f - SCALE_) * (float)ys[c] + xr[c];
      vals[ii] = v; s += v; ss += v * v;
    }
    ln_row(vals, s, ss, g, bln, orow, red);
    return;
  }
  bid -= nMain;
  if (bid < nMain * KN_) {
    const int i1 = bid % KN_;
    const int bt = bid / KN_;
    const int bbb = bt / TM1, t = bt % TM1;
    const int b = b0 + bbb;
    const bf16_t* pn = poutnb + ((size_t)bt * KC5 + 1 + i1) * C_;
    const bf16_t* nr = nrcbf + ((size_t)bt * KN_ + i1) * C_;
    float* orow = dout1 + (((size_t)(b * TM1) + t) * KN_ + i1) * C_;
    #pragma unroll
    for (int ii = 0; ii < 3; ++ii) {
      int c = threadIdx.x + ii * 256;
      float v = (float)pn[c] + (float)nr[c];
      vals[ii] = v; s += v; ss += v * v;
    }
    ln_row(vals, s, ss, g, bln, orow, red);
    return;
  }
  bid -= nMain * KN_;
  const int b = bid;
  const float* yc = ycp + (size_t)b * C_;
  const float* xr = x + (size_t)(b * T_) * C_;
  float* orow = dout + (size_t)(b * T_) * C_;
  #pragma unroll
  for (int ii = 0; ii < 3; ++ii) {
    int c = threadIdx.x + ii * 256;
    float v = yc[c] + xr[c];
    vals[ii] = v; s += v; ss += v * v;
  }
  ln_row(vals, s, ss, g, bln, orow, red);
}

// ---------------------------------------------------------------------------
extern "C" void kernel_launch(void* const* d_in, const int* in_sizes, int n_in,
                              void* d_out, int out_size, void* d_ws, size_t ws_size,
                              hipStream_t stream) {
  (void)in_sizes; (void)n_in; (void)out_size;
  const float* x    = (const float*)d_in[0];
  const int*   mask = (const int*)d_in[1];
  const float* nrep = (const float*)d_in[2];
  const float* Wq = (const float*)d_in[3];  const float* bq = (const float*)d_in[4];
  const float* Wk = (const float*)d_in[5];  const float* bk = (const float*)d_in[6];
  const float* Wv = (const float*)d_in[7];  const float* bv = (const float*)d_in[8];
  const float* Wp = (const float*)d_in[9];  const float* bp = (const float*)d_in[10];
  const float* Wd = (const float*)d_in[11]; const float* bd = (const float*)d_in[12];
  const float* Wu = (const float*)d_in[13]; const float* bu = (const float*)d_in[14];
  const float* lng = (const float*)d_in[15];
  const float* lnb = (const float*)d_in[16];
  float* dout = (float*)d_out;
  const size_t OUT1 = (size_t)B_ * T_ * C_;

  char* ws = (char*)d_ws;
  size_t off = 0;
  auto alloc = [&](size_t bytes) -> void* {
    void* p = ws + off; off += (bytes + 255) & ~(size_t)255; return p;
  };
  const size_t NT = (size_t)NT_;
  const size_t NR = (size_t)NRR_;
  const size_t YSROWS = (size_t)B_ * TM1;

  bf16_t* xbf   = (bf16_t*)alloc(NT * C_ * 2);
  bf16_t* nrbf  = (bf16_t*)alloc(NR * C_ * 2);
  bf16_t* Wbig  = (bf16_t*)alloc((size_t)LDQ * C_ * 2);
  bf16_t* Wtp   = (bf16_t*)alloc((size_t)C_ * C_ * 2);
  bf16_t* Wvbf  = (bf16_t*)alloc((size_t)C_ * C_ * 2);
  float*  WdT   = (float*)alloc((size_t)R_ * C_ * 4);
  float*  bbig  = (float*)alloc(LDQ * 4);
  float*  zb768 = (float*)alloc(768 * 4);
  bf16_t* QKVc  = (bf16_t*)alloc(NT * LDQ * 2);
  bf16_t* Vtg   = (bf16_t*)alloc(NT * C_ * 2);
  float*  t1    = (float*)alloc(NT * R_ * 4);
  bf16_t* ysp   = (bf16_t*)alloc(YSROWS * C_ * 2);
  float*  ycp   = (float*)alloc((size_t)B_ * C_ * 4);
  const size_t fixed = off;
  const size_t perb = (size_t)TM1 * KN_ * LDVQ * 2
                    + (size_t)TM1 * KN_ * R_ * 4
                    + (size_t)TM1 * KC5 * C_ * 2 + 4 * 256;
  int nb = 1;
  for (int cand : {8, 4, 2, 1}) {
    if (fixed + perb * (size_t)cand <= ws_size) { nb = cand; break; }
  }
  bf16_t* poutnb = (bf16_t*)alloc((size_t)nb * TM1 * KC5 * C_ * 2);
  bf16_t* vqn  = (bf16_t*)alloc((size_t)nb * TM1 * KN_ * LDVQ * 2);
  float*  t2   = (float*)alloc((size_t)nb * TM1 * KN_ * R_ * 4);

  dim3 blk(256);

  // 1. PREP
  prep<<<5797, blk, 0, stream>>>(x, nrep, Wq, Wk, Wv, Wp, Wd, Wu,
                                 bq, bk, bv, bu, bp,
                                 xbf, nrbf, Wbig, Wtp, Wvbf, WdT, bbig, zb768);

  // 2. WVP: Wbig rows 1536..2303 = WvpT = WpT @ Wv
  GemmDesc dwvp;
  dwvp.A = Wtp; dwvp.lda = C_; dwvp.Bt = Wvbf; dwvp.bias = zb768;
  dwvp.Cbf = Wbig + (size_t)1536 * C_; dwvp.ldc = C_;
  dwvp.Ctr = nullptr; dwvp.trcol0 = 0; dwvp.mode = 1;
  dwvp.M = C_; dwvp.K = C_; dwvp.N = C_; dwvp.gx = 6; dwvp.nwg = 36;
  gemm_mfma_k<<<36, blk, 0, stream>>>(dwvp);

  GemmDesc dqkv;
  dqkv.A = xbf; dqkv.lda = C_; dqkv.Bt = Wbig; dqkv.bias = bbig;
  dqkv.Cbf = QKVc; dqkv.ldc = LDQ; dqkv.Ctr = Vtg; dqkv.trcol0 = 1536;
  dqkv.mode = 3; dqkv.M = (int)NT; dqkv.K = C_; dqkv.N = LDQ;
  dqkv.gx = LDQ / 128; dqkv.nwg = (LDQ / 128) * 32;

  bool first = true;
  for (int b0 = 0; b0 < B_; b0 += nb) {
    const int Mn = nb * TM1 * KN_;
    const bf16_t* nrcbf = nrbf + (size_t)b0 * TM1 * KN_ * C_;

    GemmDesc dvqn;
    dvqn.A = nrcbf; dvqn.lda = C_; dvqn.Bt = Wbig + (size_t)1536 * C_;
    dvqn.bias = bbig + 1536; dvqn.Cbf = vqn; dvqn.ldc = LDVQ;
    dvqn.Ctr = nullptr; dvqn.trcol0 = 0; dvqn.mode = 1;
    dvqn.M = Mn; dvqn.K = C_; dvqn.N = LDVQ;
    dvqn.gx = LDVQ / 128; dvqn.nwg = (LDVQ / 128) * ((Mn + 127) / 128);

    const int n0 = first ? dqkv.nwg : 0;
    const int M1 = first ? (int)NT : 0;
    const int ng1 = first ? (int)((NT + 15) / 16) : 0;
    const int ng2 = (Mn + 15) / 16;

    // 3. MEGA1: QKV(+Vp+qp) + vqn GEMMs + coalesced gemv(t1) + gemv(t2)
    mega1<<<n0 + dvqn.nwg + ng1 + ng2, blk, 0, stream>>>(
        dqkv, n0, dvqn, dvqn.nwg, xbf, nrcbf, WdT, bd, t1, M1, ng1, t2, Mn);

    // 4. FUSED ATTN + CLS + NEIGH
    const int nAttn = first ? 768 : 0;
    const int nCls  = first ? 96 : 0;
    attn_neigh<<<nAttn + nCls + nb * TM1, blk, 0, stream>>>(
        nAttn, nCls, QKVc, Vtg, mask, ysp, t1, ycp, vqn, t2, b0, poutnb);

    // 5. COMBINE
    combine_all<<<nb * TM1 * (1 + KN_) + (first ? 8 : 0), blk, 0, stream>>>(
        poutnb, ysp, x, lng, lnb, b0, dout, dout + OUT1, nrcbf, nb * TM1, ycp);

    first = false;
  }
}

// Round 20
// 219.513 us; speedup vs baseline: 1.9649x; 1.9649x over previous
//
#include <hip/hip_runtime.h>
#include <math.h>

#define C_    768
#define H_    12
#define D_    64
#define B_    8
#define T_    512
#define TM1   511
#define R_    8
#define KN_   4
#define KC5   5
#define SCALE_ 0.5f
#define EPS_  1e-12f
#define NEG_  -1000000000.0f
#define INV_  0.125f
#define LDQ   2432     /* Q|K|Vp|qp(128) */
#define QPOFF 2304
#define LDVQ  896      /* vqn row: Vp(768)|qp(128) */
#define NT_   4096
#define NRR_  16352

typedef __bf16 bf16_t;
typedef __bf16 bf16x4_t __attribute__((ext_vector_type(4)));
typedef __bf16 bf16x8_t __attribute__((ext_vector_type(8)));
typedef float  f32x4_t  __attribute__((ext_vector_type(4)));
typedef const void __attribute__((address_space(1)))* gas_t;
typedef void       __attribute__((address_space(3)))* las_t;

__device__ __forceinline__ void gl_lds16(const bf16_t* g, bf16_t* l) {
  __builtin_amdgcn_global_load_lds((gas_t)g, (las_t)l, 16, 0, 0);
}

__device__ __forceinline__ int swz(int row, int g) {
  return row * 32 + (((g ^ (row >> 1)) & 3) << 3);
}

struct GemmDesc {
  const bf16_t* A; int lda;
  const bf16_t* Bt;
  const float* bias;
  bf16_t* Cbf; int ldc;
  bf16_t* Ctr; int trcol0; int mode;
  int M, K, N, gx, nwg;
};

// ---------------------------------------------------------------------------
// PREP: conversions + weight prep (round-15/16 verified).
// ---------------------------------------------------------------------------
__global__ __launch_bounds__(256) void prep(
    const float* __restrict__ x, const float* __restrict__ nrep,
    const float* __restrict__ Wq, const float* __restrict__ Wk,
    const float* __restrict__ Wv, const float* __restrict__ Wp,
    const float* __restrict__ Wd, const float* __restrict__ Wu,
    const float* __restrict__ bq, const float* __restrict__ bk,
    const float* __restrict__ bv, const float* __restrict__ bu,
    const float* __restrict__ bp,
    bf16_t* __restrict__ xbf, bf16_t* __restrict__ nrbf,
    bf16_t* __restrict__ Wbig, bf16_t* __restrict__ Wtp,
    bf16_t* __restrict__ Wvbf,
    float* __restrict__ WdT, float* __restrict__ bbig,
    float* __restrict__ zb768)
{
  __shared__ float tile[32][33];
  const int bid = blockIdx.x, tid = threadIdx.x;
  if (bid < 1024) {
    const long n = (long)NT_ * C_;
    for (long i = ((long)bid * 256 + tid) * 4; i < n; i += (long)1024 * 256 * 4) {
      float4 v = *(const float4*)(x + i);
      bf16x4_t o = {(bf16_t)v.x, (bf16_t)v.y, (bf16_t)v.z, (bf16_t)v.w};
      *(bf16x4_t*)(xbf + i) = o;
    }
  } else if (bid < 3072) {
    const long n = (long)NRR_ * C_;
    for (long i = ((long)(bid - 1024) * 256 + tid) * 4; i < n;
         i += (long)2048 * 256 * 4) {
      float4 v = *(const float4*)(nrep + i);
      bf16x4_t o = {(bf16_t)v.x, (bf16_t)v.y, (bf16_t)v.z, (bf16_t)v.w};
      *(bf16x4_t*)(nrbf + i) = o;
    }
  } else if (bid < 5376) {
    int sub = bid - 3072;
    const int which = sub / 576; sub %= 576;
    if (which == 2) {
      const long i = ((long)sub * 256 + tid) * 4;
      float4 v = *(const float4*)(Wv + i);
      bf16x4_t o = {(bf16_t)v.x, (bf16_t)v.y, (bf16_t)v.z, (bf16_t)v.w};
      *(bf16x4_t*)(Wvbf + i) = o;
    } else {
      const float* W = which == 0 ? Wq : which == 1 ? Wk : Wp;
      bf16_t* Wt = (which == 3) ? Wtp : Wbig + (size_t)which * C_ * C_;
      const int n0 = (sub % 24) * 32, k0 = (sub / 24) * 32;
      const int tx = tid & 31, ty = tid >> 5;
      #pragma unroll
      for (int r = ty; r < 32; r += 8)
        tile[r][tx] = W[(size_t)(k0 + r) * C_ + n0 + tx];
      __syncthreads();
      #pragma unroll
      for (int r = ty; r < 32; r += 8)
        Wt[(size_t)(n0 + r) * C_ + k0 + tx] = (bf16_t)tile[tx][r];
    }
  } else if (bid < 5760) {
    const int idx = (bid - 5376) * 256 + tid;
    const int n = idx / C_, k = idx % C_;
    const int h = n / 10, r = n % 10;
    float s = 0.f;
    if (h < H_ && r < 9) {
      if (r < 8) {
        #pragma unroll 8
        for (int j = 0; j < 64; ++j)
          s += Wu[r * C_ + h * 64 + j] * Wq[(size_t)k * C_ + h * 64 + j];
      } else {
        #pragma unroll 8
        for (int j = 0; j < 64; ++j)
          s += bu[h * 64 + j] * Wq[(size_t)k * C_ + h * 64 + j];
      }
    }
    Wbig[(size_t)(QPOFF + n) * C_ + k] = (bf16_t)s;
  } else if (bid < 5784) {
    const int idx = (bid - 5760) * 256 + tid;
    if (idx < R_ * C_) {
      const int r = idx / C_, k = idx % C_;
      WdT[idx] = Wd[(size_t)k * R_ + r];
    }
  } else {
    const int i = (bid - 5784) * 256 + tid;
    if (i < LDQ) {
      float v;
      if (i < 768) v = bq[i];
      else if (i < 1536) v = bk[i - 768];
      else if (i < 2304) {
        const int n = i - 1536;
        float s = bp[n];
        for (int m = 0; m < C_; ++m) s += bv[m] * Wp[(size_t)m * C_ + n];
        v = s;
      } else {
        const int n = i - QPOFF, h = n / 10, r = n % 10;
        v = 0.f;
        if (h < H_ && r < 9) {
          if (r < 8) {
            float s = 0.f;
            for (int j = 0; j < 64; ++j) s += bq[h * 64 + j] * Wu[r * C_ + h * 64 + j];
            v = s;
          } else {
            float s = 0.f;
            for (int j = 0; j < 64; ++j) s += bq[h * 64 + j] * bu[h * 64 + j];
            v = s;
          }
        }
      }
      bbig[i] = v;
    } else if (i < LDQ + 768) {
      zb768[i - LDQ] = 0.f;
    }
  }
}

// ---------------------------------------------------------------------------
// GEMM body: 128x128 tile, BK=32 double-buffered, counted vmcnt(4) pipeline
// (round-18 measured structure).
// ---------------------------------------------------------------------------
__device__ __forceinline__ void gemm_body(const GemmDesc& d, int bid0, char* pool)
{
  bf16_t* Cs = (bf16_t*)pool;

  int lid = bid0;
  {
    const int nwg = d.nwg;
    const int q0 = nwg >> 3, r0 = nwg & 7;
    const int xcd = lid & 7, idx = lid >> 3;
    lid = (xcd < r0 ? xcd * (q0 + 1) : r0 * (q0 + 1) + (xcd - r0) * q0) + idx;
  }
  const int row0 = (lid / d.gx) * 128;
  const int col0 = (lid % d.gx) * 128;

  const int tid = threadIdx.x;
  const int lane = tid & 63;
  const int wv = tid >> 6;
  const int wr = (wv >> 1) * 64;
  const int wc = (wv & 1) * 64;
  const int wvo = wv * 512;

  const int sr = tid >> 2;
  const int ssl = (tid & 3) ^ ((sr >> 1) & 3);
  const int sk = ssl * 8;

  int ra0 = row0 + sr;       if (ra0 > d.M - 1) ra0 = d.M - 1;
  int ra1 = row0 + 64 + sr;  if (ra1 > d.M - 1) ra1 = d.M - 1;
  const bf16_t* ga0 = d.A + (size_t)ra0 * d.lda + sk;
  const bf16_t* ga1 = d.A + (size_t)ra1 * d.lda + sk;
  const bf16_t* gb0 = d.Bt + (size_t)(col0 + sr) * d.K + sk;
  const bf16_t* gb1 = d.Bt + (size_t)(col0 + 64 + sr) * d.K + sk;

  f32x4_t acc[4][4];
  #pragma unroll
  for (int i = 0; i < 4; ++i)
    #pragma unroll
    for (int j = 0; j < 4; ++j) acc[i][j] = (f32x4_t){0.f, 0.f, 0.f, 0.f};

  const int fm = lane & 15;
  const int g = lane >> 4;

  {
    bf16_t* a0 = (bf16_t*)pool;
    bf16_t* b0 = (bf16_t*)(pool + 8192);
    gl_lds16(ga0, a0 + wvo);
    gl_lds16(ga1, a0 + 2048 + wvo);
    gl_lds16(gb0, b0 + wvo);
    gl_lds16(gb1, b0 + 2048 + wvo);
  }

  unsigned cur = 0;
  for (int k0 = 0; k0 < d.K; k0 += 32) {
    if (k0 + 32 < d.K) {
      char* nb = pool + ((cur ^ 1u) << 14);
      bf16_t* na = (bf16_t*)nb;
      bf16_t* nbb = (bf16_t*)(nb + 8192);
      gl_lds16(ga0 + k0 + 32, na + wvo);
      gl_lds16(ga1 + k0 + 32, na + 2048 + wvo);
      gl_lds16(gb0 + k0 + 32, nbb + wvo);
      gl_lds16(gb1 + k0 + 32, nbb + 2048 + wvo);
      asm volatile("s_waitcnt vmcnt(4)" ::: "memory");
    } else {
      asm volatile("s_waitcnt vmcnt(0)" ::: "memory");
    }
    __builtin_amdgcn_s_barrier();
    {
      const bf16_t* cA = (const bf16_t*)(pool + (cur << 14));
      const bf16_t* cB = (const bf16_t*)(pool + (cur << 14) + 8192);
      bf16x8_t af[4], bfr[4];
      #pragma unroll
      for (int mi = 0; mi < 4; ++mi)
        af[mi] = *(const bf16x8_t*)(cA + swz(wr + mi * 16 + fm, g));
      #pragma unroll
      for (int ni = 0; ni < 4; ++ni)
        bfr[ni] = *(const bf16x8_t*)(cB + swz(wc + ni * 16 + fm, g));
      __builtin_amdgcn_s_setprio(1);
      #pragma unroll
      for (int mi = 0; mi < 4; ++mi)
        #pragma unroll
        for (int ni = 0; ni < 4; ++ni)
          acc[mi][ni] = __builtin_amdgcn_mfma_f32_16x16x32_bf16(af[mi], bfr[ni],
                                                                acc[mi][ni], 0, 0, 0);
      __builtin_amdgcn_s_setprio(0);
    }
    __builtin_amdgcn_s_barrier();
    cur ^= 1u;
  }

  const int r4 = (lane >> 4) * 4;

  if (d.mode & 2) {
    #pragma unroll
    for (int ni = 0; ni < 4; ++ni) {
      const int col = col0 + wc + ni * 16 + fm;
      if ((unsigned)(col - d.trcol0) < 768u) {
        const int vcol = col - d.trcol0;
        const float bv = d.bias[col];
        #pragma unroll
        for (int mi = 0; mi < 4; ++mi) {
          const int rb = row0 + wr + mi * 16 + r4;
          bf16x4_t o4 = {(bf16_t)(acc[mi][ni][0] + bv), (bf16_t)(acc[mi][ni][1] + bv),
                         (bf16_t)(acc[mi][ni][2] + bv), (bf16_t)(acc[mi][ni][3] + bv)};
          size_t idx = ((size_t)(rb >> 9) * H_ + (size_t)(vcol >> 6)) * ((size_t)D_ * T_)
                     + (size_t)(vcol & 63) * T_ + (size_t)(rb & 511);
          *(bf16x4_t*)(d.Ctr + idx) = o4;
        }
      }
    }
  }

  #pragma unroll
  for (int p = 0; p < 2; ++p) {
    if (wr == p * 64) {
      #pragma unroll
      for (int ni = 0; ni < 4; ++ni) {
        const int col = wc + ni * 16 + fm;
        const float bv = d.bias[col0 + col];
        #pragma unroll
        for (int mi = 0; mi < 4; ++mi) {
          const int lrow = mi * 16 + r4;
          #pragma unroll
          for (int r = 0; r < 4; ++r)
            Cs[(lrow + r) * 136 + col] = (bf16_t)(acc[mi][ni][r] + bv);
        }
      }
    }
    __syncthreads();
    const int rrow = tid >> 2;
    const int cc = (tid & 3) * 32;
    const int grow = row0 + p * 64 + rrow;
    if ((d.mode & 1) && grow < d.M) {
      bf16_t* gp = d.Cbf + (size_t)grow * d.ldc + col0 + cc;
      const bf16_t* lp = Cs + rrow * 136 + cc;
      #pragma unroll
      for (int j = 0; j < 4; ++j)
        *(bf16x8_t*)(gp + j * 8) = *(const bf16x8_t*)(lp + j * 8);
    }
    __syncthreads();
  }
}

// ---------------------------------------------------------------------------
// Coalesced low-rank GEMV (round-11 verified).
// ---------------------------------------------------------------------------
__device__ __forceinline__ void gemv8w_body(
    const bf16_t* __restrict__ A, const float* __restrict__ WdT,
    const float* __restrict__ bd, float* __restrict__ out, int M, int bid)
{
  const int w = (int)threadIdx.x >> 6, lane = (int)threadIdx.x & 63;
  const int row0 = bid * 16 + w * 4;
  #pragma unroll
  for (int rr = 0; rr < 4; ++rr) {
    const int row = row0 + rr;
    if (row >= M) return;
    const bf16_t* ar = A + (size_t)row * C_ + lane * 12;
    float xv[12];
    #pragma unroll
    for (int c = 0; c < 3; ++c) {
      bf16x4_t v = *(const bf16x4_t*)(ar + c * 4);
      #pragma unroll
      for (int j = 0; j < 4; ++j) xv[c * 4 + j] = (float)v[j];
    }
    float acc[8];
    #pragma unroll
    for (int r = 0; r < 8; ++r) {
      const float* wr = WdT + r * C_ + lane * 12;
      float4 w0 = *(const float4*)(wr);
      float4 w1 = *(const float4*)(wr + 4);
      float4 w2 = *(const float4*)(wr + 8);
      acc[r] = xv[0]*w0.x + xv[1]*w0.y + xv[2]*w0.z + xv[3]*w0.w
             + xv[4]*w1.x + xv[5]*w1.y + xv[6]*w1.z + xv[7]*w1.w
             + xv[8]*w2.x + xv[9]*w2.y + xv[10]*w2.z + xv[11]*w2.w;
    }
    #pragma unroll
    for (int off = 32; off > 0; off >>= 1) {
      #pragma unroll
      for (int r = 0; r < 8; ++r) acc[r] += __shfl_xor(acc[r], off);
    }
    if (lane == 0) {
      #pragma unroll
      for (int r = 0; r < 8; ++r)
        out[(size_t)row * R_ + r] = acc[r] + bd[r];
    }
  }
}

// MEGA1: QKV-GEMM | vqn-GEMM | gemv(t1) | gemv(t2) in one dispatch.
__global__ __launch_bounds__(256) void mega1(
    GemmDesc d0, int n0, GemmDesc d1, int n1,
    const bf16_t* Ag1, const bf16_t* Ag2,
    const float* WdT, const float* bd,
    float* o1, int M1, int ng1, float* o2, int M2)
{
  __shared__ __align__(16) char pool[32768];
  int bid = blockIdx.x;
  if (bid < n0) { gemm_body(d0, bid, pool); return; }
  bid -= n0;
  if (bid < n1) { gemm_body(d1, bid, pool); return; }
  bid -= n1;
  if (bid < ng1) { gemv8w_body(Ag1, WdT, bd, o1, M1, bid); return; }
  bid -= ng1;
  gemv8w_body(Ag2, WdT, bd, o2, M2, bid);
}

// standalone GEMM (wvp weight fusion)
__global__ __launch_bounds__(256) void gemm_mfma_k(GemmDesc d) {
  __shared__ __align__(16) char pool[32768];
  gemm_body(d, blockIdx.x, pool);
}

// ---------------------------------------------------------------------------
// attn / cls / neigh bodies (round-17/18 verified).
// ---------------------------------------------------------------------------
__device__ void attn_body(
    const bf16_t* __restrict__ QKVc, const bf16_t* __restrict__ Vtg,
    const int* __restrict__ mask, bf16_t* __restrict__ yout,
    char* pool, int bid)
{
  bf16_t* Ks   = (bf16_t*)pool;
  bf16_t* Vs   = (bf16_t*)(pool + 8192);
  bf16_t* Pl   = (bf16_t*)(pool + 16384);
  float* fac_s = (float*)(pool + 24576);
  float* l_s   = (float*)(pool + 24832);
  int*   msk_s = (int*)(pool + 25088);

  const int qt0 = (bid & 7) * 64;
  const int h = (bid >> 3) % H_;
  const int b = bid / 96;
  const int tid = threadIdx.x;
  const int lane = tid & 63;
  const int w = tid >> 6;
  const int lq = lane & 15;
  const int g = lane >> 4;

  const int qi_frag = qt0 + w * 16 + lq;
  const int qtok = (qi_frag < TM1 ? qi_frag : TM1 - 1) + 1;
  bf16x8_t qf[2];
  {
    const bf16_t* qp = QKVc + ((size_t)(b * T_) + qtok) * LDQ + h * D_ + 8 * g;
    qf[0] = *(const bf16x8_t*)qp;
    qf[1] = *(const bf16x8_t*)(qp + 32);
  }

  const bf16_t* kbase = QKVc + (size_t)(b * T_) * LDQ + 768 + h * D_;
  const bf16_t* vbase = Vtg + ((size_t)(b * H_) + h) * ((size_t)D_ * T_);

  f32x4_t o[4];
  #pragma unroll
  for (int i = 0; i < 4; ++i) o[i] = (f32x4_t){0.f, 0.f, 0.f, 0.f};
  float m = -INFINITY, l = 0.f;

  for (int kt = 0; kt < T_; kt += 64) {
    #pragma unroll
    for (int i = 0; i < 2; ++i) {
      const int tp = tid + i * 256;
      const int kr = tp >> 3;
      const int sl = tp & 7;
      const int ss = sl ^ (kr & 7);
      gl_lds16(kbase + (size_t)(kt + kr) * LDQ + 8 * ss,
               Ks + (size_t)(i * 4 + w) * 512);
      gl_lds16(vbase + (size_t)kr * T_ + kt + 8 * ss,
               Vs + (size_t)(i * 4 + w) * 512);
    }
    if (tid < 64) msk_s[tid] = mask[b * T_ + kt + tid];
    __syncthreads();

    f32x4_t st[4];
    __builtin_amdgcn_s_setprio(1);
    #pragma unroll
    for (int t = 0; t < 4; ++t) {
      st[t] = (f32x4_t){0.f, 0.f, 0.f, 0.f};
      const int kk = t * 16 + lq;
      const bf16_t* krow = Ks + kk * 64;
      bf16x8_t kf0 = *(const bf16x8_t*)(krow + 8 * ((g)     ^ (kk & 7)));
      bf16x8_t kf1 = *(const bf16x8_t*)(krow + 8 * ((4 + g) ^ (kk & 7)));
      st[t] = __builtin_amdgcn_mfma_f32_16x16x32_bf16(kf0, qf[0], st[t], 0, 0, 0);
      st[t] = __builtin_amdgcn_mfma_f32_16x16x32_bf16(kf1, qf[1], st[t], 0, 0, 0);
    }
    __builtin_amdgcn_s_setprio(0);

    float p[16];
    float mt = -INFINITY;
    #pragma unroll
    for (int t = 0; t < 4; ++t) {
      const int4 mk = *(const int4*)&msk_s[t * 16 + 4 * g];
      p[4*t+0] = mk.x ? st[t][0] * INV_ : NEG_;
      p[4*t+1] = mk.y ? st[t][1] * INV_ : NEG_;
      p[4*t+2] = mk.z ? st[t][2] * INV_ : NEG_;
      p[4*t+3] = mk.w ? st[t][3] * INV_ : NEG_;
      mt = fmaxf(mt, fmaxf(fmaxf(p[4*t], p[4*t+1]), fmaxf(p[4*t+2], p[4*t+3])));
    }
    mt = fmaxf(mt, __shfl_xor(mt, 16));
    mt = fmaxf(mt, __shfl_xor(mt, 32));
    const float mnew = fmaxf(m, mt);
    const float fac = __expf(m - mnew);
    float ps = 0.f;
    #pragma unroll
    for (int i = 0; i < 16; ++i) { p[i] = __expf(p[i] - mnew); ps += p[i]; }
    ps += __shfl_xor(ps, 16);
    ps += __shfl_xor(ps, 32);
    l = l * fac + ps;
    m = mnew;
    if (lane < 16) fac_s[w * 16 + lane] = fac;

    bf16_t* prow = Pl + w * 1024 + lq * 64;
    #pragma unroll
    for (int t = 0; t < 4; ++t) {
      bf16x4_t pb = {(bf16_t)p[4*t], (bf16_t)p[4*t+1],
                     (bf16_t)p[4*t+2], (bf16_t)p[4*t+3]};
      *(bf16x4_t*)(prow + 8 * ((2*t + (g >> 1)) ^ (lq & 7)) + 4 * (g & 1)) = pb;
    }
    bf16x8_t pa0 = *(const bf16x8_t*)(prow + 8 * ((g)     ^ (lq & 7)));
    bf16x8_t pa1 = *(const bf16x8_t*)(prow + 8 * ((4 + g) ^ (lq & 7)));

    const float4 fc = *(const float4*)&fac_s[w * 16 + 4 * g];
    __builtin_amdgcn_s_setprio(1);
    #pragma unroll
    for (int db = 0; db < 4; ++db) {
      const int dr = db * 16 + lq;
      const bf16_t* vrow = Vs + dr * 64;
      bf16x8_t vf0 = *(const bf16x8_t*)(vrow + 8 * ((g)     ^ (dr & 7)));
      bf16x8_t vf1 = *(const bf16x8_t*)(vrow + 8 * ((4 + g) ^ (dr & 7)));
      o[db][0] *= fc.x; o[db][1] *= fc.y; o[db][2] *= fc.z; o[db][3] *= fc.w;
      o[db] = __builtin_amdgcn_mfma_f32_16x16x32_bf16(pa0, vf0, o[db], 0, 0, 0);
      o[db] = __builtin_amdgcn_mfma_f32_16x16x32_bf16(pa1, vf1, o[db], 0, 0, 0);
    }
    __builtin_amdgcn_s_setprio(0);
    __syncthreads();
  }

  if (lane < 16) l_s[w * 16 + lane] = l;
  const float4 lv = *(const float4*)&l_s[w * 16 + 4 * g];
  const float rl0 = 1.f / lv.x, rl1 = 1.f / lv.y;
  const float rl2 = 1.f / lv.z, rl3 = 1.f / lv.w;
  const int qr0 = qt0 + w * 16 + 4 * g;
  #pragma unroll
  for (int db = 0; db < 4; ++db) {
    const int col = h * D_ + db * 16 + lq;
    bf16_t* yp = yout + ((size_t)(b * TM1) + qr0) * C_ + col;
    if (qr0 + 0 < TM1) yp[0 * (size_t)C_] = (bf16_t)(o[db][0] * rl0);
    if (qr0 + 1 < TM1) yp[1 * (size_t)C_] = (bf16_t)(o[db][1] * rl1);
    if (qr0 + 2 < TM1) yp[2 * (size_t)C_] = (bf16_t)(o[db][2] * rl2);
    if (qr0 + 3 < TM1) yp[3 * (size_t)C_] = (bf16_t)(o[db][3] * rl3);
  }
}

__device__ void cls_body(
    const bf16_t* __restrict__ QKVc, const float* __restrict__ t1,
    const int* __restrict__ mask, float* __restrict__ ycp,
    char* pool, int cbid)
{
  float* Vs   = (float*)pool;
  float* Ps   = (float*)(pool + 16640);
  float* qp_s = (float*)(pool + 16960);

  const int b = cbid / H_, h = cbid % H_;
  const int tid = threadIdx.x;
  const int lane = tid & 63;

  if (tid < 9)
    qp_s[tid] = (float)QKVc[(size_t)(b * T_) * LDQ + QPOFF + h * 10 + tid];
  __syncthreads();

  float m = -INFINITY, l = 0.f, acc = 0.f, mnew = 0.f;
  for (int kt = 0; kt < T_; kt += 64) {
    for (int rr = tid >> 6; rr < 64; rr += 4)
      Vs[rr * 65 + lane] =
          (float)QKVc[((size_t)(b * T_) + kt + rr) * LDQ + 1536 + h * D_ + lane];
    __syncthreads();
    if (tid < 64) {
      const float* t1r = t1 + ((size_t)(b * T_) + kt + tid) * R_;
      float sc = qp_s[8];
      #pragma unroll
      for (int r = 0; r < 8; ++r) sc += qp_s[r] * t1r[r];
      sc *= INV_;
      if (!mask[b * T_ + kt + tid]) sc = NEG_;
      float mt = sc;
      #pragma unroll
      for (int off = 32; off > 0; off >>= 1) mt = fmaxf(mt, __shfl_xor(mt, off));
      mnew = fmaxf(m, mt);
      float e = __expf(sc - mnew);
      float ssum = e;
      #pragma unroll
      for (int off = 32; off > 0; off >>= 1) ssum += __shfl_xor(ssum, off);
      float fac = __expf(m - mnew);
      acc *= fac;
      l = l * fac + ssum;
      Ps[tid] = e;
    }
    __syncthreads();
    if (tid < 64) {
      #pragma unroll
      for (int j = 0; j < 64; ++j) acc += Ps[j] * Vs[j * 65 + tid];
      m = mnew;
    }
    __syncthreads();
  }
  if (tid < 64) ycp[(size_t)b * C_ + h * D_ + tid] = acc / l;
}

__device__ void neigh_body(
    const bf16_t* __restrict__ QKVc, const float* __restrict__ t1,
    const bf16_t* __restrict__ vqn, const float* __restrict__ t2,
    int b0, bf16_t* __restrict__ poutn, char* pool, int bt)
{
  float* vs   = (float*)pool;
  float* qp_s = (float*)(pool + 15360);
  float* t2_s = (float*)(pool + 17920);
  float* Ps   = (float*)(pool + 18080);

  const int tid = threadIdx.x;
  const int bb = bt / TM1, t = bt % TM1;
  const int b = b0 + bb;
  const size_t tok = (size_t)(b * T_) + t + 1;
  const size_t nrow = ((size_t)(bb * TM1) + t) * KN_;

  for (int idx = tid; idx < KC5 * 96; idx += 256) {
    int i = idx / 96, d8 = (idx % 96) * 8;
    const bf16_t* vp = (i == 0) ? QKVc + tok * LDQ + 1536 + d8
                                : vqn + (nrow + i - 1) * LDVQ + d8;
    bf16x8_t vv = *(const bf16x8_t*)vp;
    #pragma unroll
    for (int j = 0; j < 8; ++j) vs[i * C_ + d8 + j] = (float)vv[j];
  }
  for (int idx = tid; idx < KC5 * 16; idx += 256) {
    int i = idx / 16, c8 = (idx % 16) * 8;
    const bf16_t* qpp = (i == 0) ? QKVc + tok * LDQ + QPOFF + c8
                                 : vqn + (nrow + i - 1) * LDVQ + 768 + c8;
    bf16x8_t qv = *(const bf16x8_t*)qpp;
    #pragma unroll
    for (int j = 0; j < 8; ++j) qp_s[i * 128 + c8 + j] = (float)qv[j];
  }
  if (tid < KC5 * 8) {
    int i = tid / 8, r = tid & 7;
    t2_s[i * 8 + r] = (i == 0) ? t1[tok * R_ + r] : t2[(nrow + i - 1) * R_ + r];
  }
  __syncthreads();

  if (tid < H_ * KC5) {
    int h = tid / KC5, i = tid % KC5;
    float sc[KC5];
    #pragma unroll
    for (int j = 0; j < KC5; ++j) {
      float s = qp_s[i * 128 + h * 10 + 8];
      #pragma unroll
      for (int r = 0; r < 8; ++r) s += qp_s[i * 128 + h * 10 + r] * t2_s[j * 8 + r];
      sc[j] = s * INV_;
    }
    float mt = sc[0];
    #pragma unroll
    for (int j = 1; j < KC5; ++j) mt = fmaxf(mt, sc[j]);
    float e[KC5], ssum = 0.f;
    #pragma unroll
    for (int j = 0; j < KC5; ++j) { e[j] = __expf(sc[j] - mt); ssum += e[j]; }
    float rs = 1.f / ssum;
    #pragma unroll
    for (int j = 0; j < KC5; ++j) Ps[h * 25 + i * KC5 + j] = e[j] * rs;
  }
  __syncthreads();

  for (int idx = tid; idx < KC5 * C_; idx += 256) {
    int i = idx / C_, c = idx % C_;
    int h = c / D_;
    float sum = 0.f;
    #pragma unroll
    for (int j = 0; j < KC5; ++j)
      sum += Ps[h * 25 + i * KC5 + j] * vs[j * C_ + c];
    poutn[(((size_t)(bb * TM1) + t) * KC5 + i) * C_ + c] = (bf16_t)sum;
  }
}

__global__ __launch_bounds__(256) void attn_neigh(
    int nAttn, int nCls,
    const bf16_t* __restrict__ QKVc, const bf16_t* __restrict__ Vtg,
    const int* __restrict__ mask, bf16_t* __restrict__ ysp,
    const float* __restrict__ t1, float* __restrict__ ycp,
    const bf16_t* __restrict__ vqn, const float* __restrict__ t2,
    int b0, bf16_t* __restrict__ poutn)
{
  __shared__ __align__(16) char pool[25344];
  int bid = blockIdx.x;
  if (bid < nAttn) { attn_body(QKVc, Vtg, mask, ysp, pool, bid); return; }
  bid -= nAttn;
  if (bid < nCls) { cls_body(QKVc, t1, mask, ycp, pool, bid); return; }
  bid -= nCls;
  neigh_body(QKVc, t1, vqn, t2, b0, poutn, pool, bid);
}

// ---------------------------------------------------------------------------
// COMBINE: main (with y_self blend) + neigh + cls residual-LN.
// ---------------------------------------------------------------------------
__device__ __forceinline__ void block_reduce2(float& s, float& ss, float* red) {
  #pragma unroll
  for (int off = 32; off > 0; off >>= 1) {
    s += __shfl_down(s, off);
    ss += __shfl_down(ss, off);
  }
  int wid = threadIdx.x >> 6;
  if ((threadIdx.x & 63) == 0) { red[wid * 2] = s; red[wid * 2 + 1] = ss; }
  __syncthreads();
  s  = red[0] + red[2] + red[4] + red[6];
  ss = red[1] + red[3] + red[5] + red[7];
}

__device__ __forceinline__ void ln_row(const float vals[3], float s, float ss,
                                       const float* __restrict__ g,
                                       const float* __restrict__ bb,
                                       float* __restrict__ orow, float* red) {
  block_reduce2(s, ss, red);
  float mean = s * (1.f / (float)C_);
  float var = ss * (1.f / (float)C_) - mean * mean;
  var = fmaxf(var, 0.f);
  float rs = rsqrtf(var + EPS_);
  #pragma unroll
  for (int ii = 0; ii < 3; ++ii) {
    int c = threadIdx.x + ii * 256;
    orow[c] = (vals[ii] - mean) * rs * g[c] + bb[c];
  }
}

__global__ __launch_bounds__(256) void combine_all(
    const bf16_t* __restrict__ poutnb, const bf16_t* __restrict__ ysp,
    const float* __restrict__ x,
    const float* __restrict__ g, const float* __restrict__ bln,
    int b0, float* __restrict__ dout, float* __restrict__ dout1,
    const bf16_t* __restrict__ nrcbf, int nMain,
    const float* __restrict__ ycp)
{
  __shared__ float red[8];
  int bid = blockIdx.x;
  float vals[3], s = 0.f, ss = 0.f;
  if (bid < nMain) {
    const int bbb = bid / TM1, t = bid % TM1;
    const int b = b0 + bbb;
    const bf16_t* pn = poutnb + (((size_t)(bbb * TM1) + t) * KC5 + 0) * C_;
    const bf16_t* ys = ysp + ((size_t)(b * TM1) + t) * C_;
    const float* xr = x + ((size_t)(b * T_) + t + 1) * C_;
    float* orow = dout + ((size_t)(b * T_) + t + 1) * C_;
    #pragma unroll
    for (int ii = 0; ii < 3; ++ii) {
      int c = threadIdx.x + ii * 256;
      float v = SCALE_ * (float)pn[c] + (1.f - SCALE_) * (float)ys[c] + xr[c];
      vals[ii] = v; s += v; ss += v * v;
    }
    ln_row(vals, s, ss, g, bln, orow, red);
    return;
  }
  bid -= nMain;
  if (bid < nMain * KN_) {
    const int i1 = bid % KN_;
    const int bt = bid / KN_;
    const int bbb = bt / TM1, t = bt % TM1;
    const int b = b0 + bbb;
    const bf16_t* pn = poutnb + ((size_t)bt * KC5 + 1 + i1) * C_;
    const bf16_t* nr = nrcbf + ((size_t)bt * KN_ + i1) * C_;
    float* orow = dout1 + (((size_t)(b * TM1) + t) * KN_ + i1) * C_;
    #pragma unroll
    for (int ii = 0; ii < 3; ++ii) {
      int c = threadIdx.x + ii * 256;
      float v = (float)pn[c] + (float)nr[c];
      vals[ii] = v; s += v; ss += v * v;
    }
    ln_row(vals, s, ss, g, bln, orow, red);
    return;
  }
  bid -= nMain * KN_;
  const int b = bid;
  const float* yc = ycp + (size_t)b * C_;
  const float* xr = x + (size_t)(b * T_) * C_;
  float* orow = dout + (size_t)(b * T_) * C_;
  #pragma unroll
  for (int ii = 0; ii < 3; ++ii) {
    int c = threadIdx.x + ii * 256;
    float v = yc[c] + xr[c];
    vals[ii] = v; s += v; ss += v * v;
  }
  ln_row(vals, s, ss, g, bln, orow, red);
}

// ---------------------------------------------------------------------------
extern "C" void kernel_launch(void* const* d_in, const int* in_sizes, int n_in,
                              void* d_out, int out_size, void* d_ws, size_t ws_size,
                              hipStream_t stream) {
  (void)in_sizes; (void)n_in; (void)out_size;
  const float* x    = (const float*)d_in[0];
  const int*   mask = (const int*)d_in[1];
  const float* nrep = (const float*)d_in[2];
  const float* Wq = (const float*)d_in[3];  const float* bq = (const float*)d_in[4];
  const float* Wk = (const float*)d_in[5];  const float* bk = (const float*)d_in[6];
  const float* Wv = (const float*)d_in[7];  const float* bv = (const float*)d_in[8];
  const float* Wp = (const float*)d_in[9];  const float* bp = (const float*)d_in[10];
  const float* Wd = (const float*)d_in[11]; const float* bd = (const float*)d_in[12];
  const float* Wu = (const float*)d_in[13]; const float* bu = (const float*)d_in[14];
  const float* lng = (const float*)d_in[15];
  const float* lnb = (const float*)d_in[16];
  float* dout = (float*)d_out;
  const size_t OUT1 = (size_t)B_ * T_ * C_;

  char* ws = (char*)d_ws;
  size_t off = 0;
  auto alloc = [&](size_t bytes) -> void* {
    void* p = ws + off; off += (bytes + 255) & ~(size_t)255; return p;
  };
  const size_t NT = (size_t)NT_;
  const size_t NR = (size_t)NRR_;
  const size_t YSROWS = (size_t)B_ * TM1;

  bf16_t* xbf   = (bf16_t*)alloc(NT * C_ * 2);
  bf16_t* nrbf  = (bf16_t*)alloc(NR * C_ * 2);
  bf16_t* Wbig  = (bf16_t*)alloc((size_t)LDQ * C_ * 2);
  bf16_t* Wtp   = (bf16_t*)alloc((size_t)C_ * C_ * 2);
  bf16_t* Wvbf  = (bf16_t*)alloc((size_t)C_ * C_ * 2);
  float*  WdT   = (float*)alloc((size_t)R_ * C_ * 4);
  float*  bbig  = (float*)alloc(LDQ * 4);
  float*  zb768 = (float*)alloc(768 * 4);
  bf16_t* QKVc  = (bf16_t*)alloc(NT * LDQ * 2);
  bf16_t* Vtg   = (bf16_t*)alloc(NT * C_ * 2);
  float*  t1    = (float*)alloc(NT * R_ * 4);
  bf16_t* ysp   = (bf16_t*)alloc(YSROWS * C_ * 2);
  float*  ycp   = (float*)alloc((size_t)B_ * C_ * 4);
  const size_t fixed = off;
  const size_t perb = (size_t)TM1 * KN_ * LDVQ * 2
                    + (size_t)TM1 * KN_ * R_ * 4
                    + (size_t)TM1 * KC5 * C_ * 2 + 4 * 256;
  int nb = 1;
  for (int cand : {8, 4, 2, 1}) {
    if (fixed + perb * (size_t)cand <= ws_size) { nb = cand; break; }
  }
  bf16_t* poutnb = (bf16_t*)alloc((size_t)nb * TM1 * KC5 * C_ * 2);
  bf16_t* vqn  = (bf16_t*)alloc((size_t)nb * TM1 * KN_ * LDVQ * 2);
  float*  t2   = (float*)alloc((size_t)nb * TM1 * KN_ * R_ * 4);

  dim3 blk(256);

  // 1. PREP
  prep<<<5797, blk, 0, stream>>>(x, nrep, Wq, Wk, Wv, Wp, Wd, Wu,
                                 bq, bk, bv, bu, bp,
                                 xbf, nrbf, Wbig, Wtp, Wvbf, WdT, bbig, zb768);

  // 2. WVP: Wbig rows 1536..2303 = WvpT = WpT @ Wv
  GemmDesc dwvp;
  dwvp.A = Wtp; dwvp.lda = C_; dwvp.Bt = Wvbf; dwvp.bias = zb768;
  dwvp.Cbf = Wbig + (size_t)1536 * C_; dwvp.ldc = C_;
  dwvp.Ctr = nullptr; dwvp.trcol0 = 0; dwvp.mode = 1;
  dwvp.M = C_; dwvp.K = C_; dwvp.N = C_; dwvp.gx = 6; dwvp.nwg = 36;
  gemm_mfma_k<<<36, blk, 0, stream>>>(dwvp);

  GemmDesc dqkv;
  dqkv.A = xbf; dqkv.lda = C_; dqkv.Bt = Wbig; dqkv.bias = bbig;
  dqkv.Cbf = QKVc; dqkv.ldc = LDQ; dqkv.Ctr = Vtg; dqkv.trcol0 = 1536;
  dqkv.mode = 3; dqkv.M = (int)NT; dqkv.K = C_; dqkv.N = LDQ;
  dqkv.gx = LDQ / 128; dqkv.nwg = (LDQ / 128) * 32;

  bool first = true;
  for (int b0 = 0; b0 < B_; b0 += nb) {
    const int Mn = nb * TM1 * KN_;
    const bf16_t* nrcbf = nrbf + (size_t)b0 * TM1 * KN_ * C_;

    GemmDesc dvqn;
    dvqn.A = nrcbf; dvqn.lda = C_; dvqn.Bt = Wbig + (size_t)1536 * C_;
    dvqn.bias = bbig + 1536; dvqn.Cbf = vqn; dvqn.ldc = LDVQ;
    dvqn.Ctr = nullptr; dvqn.trcol0 = 0; dvqn.mode = 1;
    dvqn.M = Mn; dvqn.K = C_; dvqn.N = LDVQ;
    dvqn.gx = LDVQ / 128; dvqn.nwg = (LDVQ / 128) * ((Mn + 127) / 128);

    const int n0 = first ? dqkv.nwg : 0;
    const int M1 = first ? (int)NT : 0;
    const int ng1 = first ? (int)((NT + 15) / 16) : 0;
    const int ng2 = (Mn + 15) / 16;

    // 3. MEGA1: QKV(+Vp+qp) + vqn GEMMs + coalesced gemv(t1) + gemv(t2)
    mega1<<<n0 + dvqn.nwg + ng1 + ng2, blk, 0, stream>>>(
        dqkv, n0, dvqn, dvqn.nwg, xbf, nrcbf, WdT, bd, t1, M1, ng1, t2, Mn);

    // 4. FUSED ATTN + CLS + NEIGH
    const int nAttn = first ? 768 : 0;
    const int nCls  = first ? 96 : 0;
    attn_neigh<<<nAttn + nCls + nb * TM1, blk, 0, stream>>>(
        nAttn, nCls, QKVc, Vtg, mask, ysp, t1, ycp, vqn, t2, b0, poutnb);

    // 5. COMBINE
    combine_all<<<nb * TM1 * (1 + KN_) + (first ? 8 : 0), blk, 0, stream>>>(
        poutnb, ysp, x, lng, lnb, b0, dout, dout + OUT1, nrcbf, nb * TM1, ycp);

    first = false;
  }
}